// Round 1
// baseline (50.248 us; speedup 1.0000x reference)
//
#include <hip/hip_runtime.h>

#define YS 14
#define L_COORD 5.0f
#define L_NOOBJ 0.5f
#define NCELLS (4096 * 14 * 14)
#define BLOCK 256
#define NBLOCKS ((NCELLS + BLOCK - 1) / BLOCK)

__global__ __launch_bounds__(BLOCK) void yolo_partial(
    const float* __restrict__ pred,
    const float* __restrict__ targ,
    float* __restrict__ partial)
{
    int cell = blockIdx.x * BLOCK + threadIdx.x;
    float loss = 0.0f;

    if (cell < NCELLS) {
        const float2* p2 = reinterpret_cast<const float2*>(pred + (size_t)cell * 30);
        const float2* t2 = reinterpret_cast<const float2*>(targ + (size_t)cell * 30);

        // channels 0..9 (two boxes) kept in registers
        float2 pA0 = p2[0], pA1 = p2[1], pA2 = p2[2], pA3 = p2[3], pA4 = p2[4];
        float2 tA0 = t2[0], tA1 = t2[1], tA2 = t2[2], tA3 = t2[3], tA4 = t2[4];

        // channels 10..29: accumulate class-loss on the fly
        float cls = 0.0f;
        #pragma unroll
        for (int k = 5; k < 15; ++k) {
            float2 a = p2[k];
            float2 b = t2[k];
            float d0 = a.x - b.x;
            float d1 = a.y - b.y;
            cls += d0 * d0 + d1 * d1;
        }

        float pv0 = pA0.x, pv1 = pA0.y, pv2 = pA1.x, pv3 = pA1.y, pv4 = pA2.x;
        float pv5 = pA2.y, pv6 = pA3.x, pv7 = pA3.y, pv8 = pA4.x, pv9 = pA4.y;
        float tv0 = tA0.x, tv1 = tA0.y, tv2 = tA1.x, tv3 = tA1.y, tv4 = tA2.x;
        float tv5 = tA2.y, tv6 = tA3.x, tv7 = tA3.y, tv8 = tA4.x, tv9 = tA4.y;

        bool obj = tv4 > 0.0f;

        if (!obj) {
            float d4 = pv4 - tv4;
            float d9 = pv9 - tv9;
            loss = L_NOOBJ * (d4 * d4 + d9 * d9);
        } else {
            // target box 0 corners
            float tcx = tv0 / 14.0f, tcy = tv1 / 14.0f;
            float t_ltx = tcx - 0.5f * tv2;
            float t_lty = tcy - 0.5f * tv3;
            float t_rbx = tcx + 0.5f * tv2;
            float t_rby = tcy + 0.5f * tv3;
            float area_t = (t_rbx - t_ltx) * (t_rby - t_lty);

            // pred box 0
            float p0cx = pv0 / 14.0f, p0cy = pv1 / 14.0f;
            float p0_ltx = p0cx - 0.5f * pv2;
            float p0_lty = p0cy - 0.5f * pv3;
            float p0_rbx = p0cx + 0.5f * pv2;
            float p0_rby = p0cy + 0.5f * pv3;
            float w0x = fmaxf(fminf(p0_rbx, t_rbx) - fmaxf(p0_ltx, t_ltx), 0.0f);
            float w0y = fmaxf(fminf(p0_rby, t_rby) - fmaxf(p0_lty, t_lty), 0.0f);
            float inter0 = w0x * w0y;
            float area_p0 = (p0_rbx - p0_ltx) * (p0_rby - p0_lty);
            float iou0 = inter0 / (area_p0 + area_t - inter0);

            // pred box 1
            float p1cx = pv5 / 14.0f, p1cy = pv6 / 14.0f;
            float p1_ltx = p1cx - 0.5f * pv7;
            float p1_lty = p1cy - 0.5f * pv8;
            float p1_rbx = p1cx + 0.5f * pv7;
            float p1_rby = p1cy + 0.5f * pv8;
            float w1x = fmaxf(fminf(p1_rbx, t_rbx) - fmaxf(p1_ltx, t_ltx), 0.0f);
            float w1y = fmaxf(fminf(p1_rby, t_rby) - fmaxf(p1_lty, t_lty), 0.0f);
            float inter1 = w1x * w1y;
            float area_p1 = (p1_rbx - p1_ltx) * (p1_rby - p1_lty);
            float iou1 = inter1 / (area_p1 + area_t - inter1);

            // argmax (tie -> box 0, matching jnp.argmax first-occurrence)
            bool best1 = iou1 > iou0;
            float max_iou = fmaxf(iou0, iou1);

            float pbr0 = best1 ? pv5 : pv0;
            float pbr1 = best1 ? pv6 : pv1;
            float pbr2 = best1 ? pv7 : pv2;
            float pbr3 = best1 ? pv8 : pv3;
            float pbr4 = best1 ? pv9 : pv4;
            float tbr0 = best1 ? tv5 : tv0;
            float tbr1 = best1 ? tv6 : tv1;
            float tbr2 = best1 ? tv7 : tv2;
            float tbr3 = best1 ? tv8 : tv3;

            float dcf = pbr4 - max_iou;
            float contain = dcf * dcf;

            float dx = pbr0 - tbr0;
            float dy = pbr1 - tbr1;
            float reg_xy = dx * dx + dy * dy;

            float dw = sqrtf(pbr2) - sqrtf(tbr2);
            float dh = sqrtf(pbr3) - sqrtf(tbr3);
            float reg_wh = dw * dw + dh * dh;

            loss = cls + contain + L_COORD * (reg_xy + reg_wh);
        }
    }

    // wave64 reduction
    #pragma unroll
    for (int off = 32; off > 0; off >>= 1)
        loss += __shfl_down(loss, off, 64);

    __shared__ float wsum[BLOCK / 64];
    int lane = threadIdx.x & 63;
    int wid = threadIdx.x >> 6;
    if (lane == 0) wsum[wid] = loss;
    __syncthreads();
    if (threadIdx.x == 0)
        partial[blockIdx.x] = wsum[0] + wsum[1] + wsum[2] + wsum[3];
}

__global__ __launch_bounds__(256) void yolo_final(
    const float* __restrict__ partial,
    float* __restrict__ out)
{
    float s = 0.0f;
    for (int i = threadIdx.x; i < NBLOCKS; i += 256)
        s += partial[i];

    #pragma unroll
    for (int off = 32; off > 0; off >>= 1)
        s += __shfl_down(s, off, 64);

    __shared__ float wsum[4];
    int lane = threadIdx.x & 63;
    int wid = threadIdx.x >> 6;
    if (lane == 0) wsum[wid] = s;
    __syncthreads();
    if (threadIdx.x == 0)
        out[0] = (wsum[0] + wsum[1] + wsum[2] + wsum[3]) * (1.0f / 4096.0f);
}

extern "C" void kernel_launch(void* const* d_in, const int* in_sizes, int n_in,
                              void* d_out, int out_size, void* d_ws, size_t ws_size,
                              hipStream_t stream) {
    const float* pred = (const float*)d_in[0];
    const float* targ = (const float*)d_in[1];
    float* out = (float*)d_out;
    float* partial = (float*)d_ws;

    yolo_partial<<<NBLOCKS, BLOCK, 0, stream>>>(pred, targ, partial);
    yolo_final<<<1, 256, 0, stream>>>(partial, out);
}

// Round 2
// 42.861 us; speedup vs baseline: 1.1723x; 1.1723x over previous
//
#include <hip/hip_runtime.h>

#define CELLS_PER_BLOCK 128
#define BLOCK 256
#define NCELLS (4096 * 14 * 14)
#define NBLOCKS (NCELLS / CELLS_PER_BLOCK)   // 6272, exact
#define STRIDE 61                            // 30 floats + pad -> odd word stride
#define F2_PER_INPUT (CELLS_PER_BLOCK * 15)  // 1920

__global__ __launch_bounds__(BLOCK) void yolo_partial(
    const float* __restrict__ pred,
    const float* __restrict__ targ,
    float* __restrict__ partial)
{
    __shared__ float lds[2 * CELLS_PER_BLOCK * STRIDE]; // 62464 B
    __shared__ float wsum[BLOCK / 64];

    const int tid = threadIdx.x;
    const size_t gbase = (size_t)blockIdx.x * CELLS_PER_BLOCK * 30;
    const float2* pp = reinterpret_cast<const float2*>(pred + gbase);
    const float2* tp = reinterpret_cast<const float2*>(targ + gbase);

    // ---- coalesced staging: issue all 15 loads first (MLP), then LDS writes
    float2 v[15];
    #pragma unroll
    for (int k = 0; k < 15; ++k) {
        int i = tid + k * BLOCK;                       // 0..3839, exact cover
        const float2* src = (i < F2_PER_INPUT) ? (pp + i) : (tp + (i - F2_PER_INPUT));
        v[k] = *src;
    }
    #pragma unroll
    for (int k = 0; k < 15; ++k) {
        int i = tid + k * BLOCK;
        int ii = (i < F2_PER_INPUT) ? i : (i - F2_PER_INPUT);
        int cell = ii / 15;
        int elem = 2 * (ii % 15);                      // even, never straddles a cell
        int off = ((i < F2_PER_INPUT) ? 0 : CELLS_PER_BLOCK * STRIDE)
                  + cell * STRIDE + elem;
        lds[off]     = v[k].x;
        lds[off + 1] = v[k].y;
    }
    __syncthreads();

    // ---- compute: one thread per cell (threads 128..255 contribute 0)
    float loss = 0.0f;
    if (tid < CELLS_PER_BLOCK) {
        const float* pc = &lds[tid * STRIDE];
        const float* tc = &lds[CELLS_PER_BLOCK * STRIDE + tid * STRIDE];

        float cls = 0.0f;
        #pragma unroll
        for (int e = 10; e < 30; ++e) {
            float d = pc[e] - tc[e];
            cls += d * d;
        }

        float pv0 = pc[0], pv1 = pc[1], pv2 = pc[2], pv3 = pc[3], pv4 = pc[4];
        float pv5 = pc[5], pv6 = pc[6], pv7 = pc[7], pv8 = pc[8], pv9 = pc[9];
        float tv0 = tc[0], tv1 = tc[1], tv2 = tc[2], tv3 = tc[3], tv4 = tc[4];
        float tv5 = tc[5], tv6 = tc[6], tv7 = tc[7], tv8 = tc[8];

        bool obj = tv4 > 0.0f;

        if (!obj) {
            float d4 = pv4 - tv4;
            float d9 = pv9 - tc[9];
            loss = 0.5f * (d4 * d4 + d9 * d9);
        } else {
            // target box 0 corners
            float tcx = tv0 / 14.0f, tcy = tv1 / 14.0f;
            float t_ltx = tcx - 0.5f * tv2;
            float t_lty = tcy - 0.5f * tv3;
            float t_rbx = tcx + 0.5f * tv2;
            float t_rby = tcy + 0.5f * tv3;
            float area_t = (t_rbx - t_ltx) * (t_rby - t_lty);

            // pred box 0
            float p0cx = pv0 / 14.0f, p0cy = pv1 / 14.0f;
            float p0_ltx = p0cx - 0.5f * pv2;
            float p0_lty = p0cy - 0.5f * pv3;
            float p0_rbx = p0cx + 0.5f * pv2;
            float p0_rby = p0cy + 0.5f * pv3;
            float w0x = fmaxf(fminf(p0_rbx, t_rbx) - fmaxf(p0_ltx, t_ltx), 0.0f);
            float w0y = fmaxf(fminf(p0_rby, t_rby) - fmaxf(p0_lty, t_lty), 0.0f);
            float inter0 = w0x * w0y;
            float area_p0 = (p0_rbx - p0_ltx) * (p0_rby - p0_lty);
            float iou0 = inter0 / (area_p0 + area_t - inter0);

            // pred box 1
            float p1cx = pv5 / 14.0f, p1cy = pv6 / 14.0f;
            float p1_ltx = p1cx - 0.5f * pv7;
            float p1_lty = p1cy - 0.5f * pv8;
            float p1_rbx = p1cx + 0.5f * pv7;
            float p1_rby = p1cy + 0.5f * pv8;
            float w1x = fmaxf(fminf(p1_rbx, t_rbx) - fmaxf(p1_ltx, t_ltx), 0.0f);
            float w1y = fmaxf(fminf(p1_rby, t_rby) - fmaxf(p1_lty, t_lty), 0.0f);
            float inter1 = w1x * w1y;
            float area_p1 = (p1_rbx - p1_ltx) * (p1_rby - p1_lty);
            float iou1 = inter1 / (area_p1 + area_t - inter1);

            bool best1 = iou1 > iou0;          // tie -> box 0 (argmax first-occurrence)
            float max_iou = fmaxf(iou0, iou1);

            float pbr0 = best1 ? pv5 : pv0;
            float pbr1 = best1 ? pv6 : pv1;
            float pbr2 = best1 ? pv7 : pv2;
            float pbr3 = best1 ? pv8 : pv3;
            float pbr4 = best1 ? pv9 : pv4;
            float tbr0 = best1 ? tv5 : tv0;
            float tbr1 = best1 ? tv6 : tv1;
            float tbr2 = best1 ? tv7 : tv2;
            float tbr3 = best1 ? tv8 : tv3;

            float dcf = pbr4 - max_iou;
            float contain = dcf * dcf;

            float dx = pbr0 - tbr0;
            float dy = pbr1 - tbr1;
            float reg_xy = dx * dx + dy * dy;

            float dw = sqrtf(pbr2) - sqrtf(tbr2);
            float dh = sqrtf(pbr3) - sqrtf(tbr3);
            float reg_wh = dw * dw + dh * dh;

            loss = cls + contain + 5.0f * (reg_xy + reg_wh);
        }
    }

    // ---- block reduction
    #pragma unroll
    for (int off = 32; off > 0; off >>= 1)
        loss += __shfl_down(loss, off, 64);

    int lane = tid & 63;
    int wid = tid >> 6;
    if (lane == 0) wsum[wid] = loss;
    __syncthreads();
    if (tid == 0)
        partial[blockIdx.x] = wsum[0] + wsum[1] + wsum[2] + wsum[3];
}

__global__ __launch_bounds__(1024) void yolo_final(
    const float* __restrict__ partial,
    float* __restrict__ out)
{
    float s = 0.0f;
    for (int i = threadIdx.x; i < NBLOCKS; i += 1024)
        s += partial[i];

    #pragma unroll
    for (int off = 32; off > 0; off >>= 1)
        s += __shfl_down(s, off, 64);

    __shared__ float wsum[16];
    int lane = threadIdx.x & 63;
    int wid = threadIdx.x >> 6;
    if (lane == 0) wsum[wid] = s;
    __syncthreads();
    if (threadIdx.x == 0) {
        float tot = 0.0f;
        #pragma unroll
        for (int w = 0; w < 16; ++w) tot += wsum[w];
        out[0] = tot * (1.0f / 4096.0f);
    }
}

extern "C" void kernel_launch(void* const* d_in, const int* in_sizes, int n_in,
                              void* d_out, int out_size, void* d_ws, size_t ws_size,
                              hipStream_t stream) {
    const float* pred = (const float*)d_in[0];
    const float* targ = (const float*)d_in[1];
    float* out = (float*)d_out;
    float* partial = (float*)d_ws;

    yolo_partial<<<NBLOCKS, BLOCK, 0, stream>>>(pred, targ, partial);
    yolo_final<<<1, 1024, 0, stream>>>(partial, out);
}

// Round 3
// 35.733 us; speedup vs baseline: 1.4062x; 1.1995x over previous
//
#include <hip/hip_runtime.h>

#define CELLS_PER_BLOCK 128
#define BLOCK 256
#define NCELLS (4096 * 14 * 14)
#define NBLOCKS (NCELLS / CELLS_PER_BLOCK)   // 6272, exact
#define STRIDE 31                            // 30 floats + 1 pad -> odd word stride
#define F2_PER_INPUT (CELLS_PER_BLOCK * 15)  // 1920

__global__ __launch_bounds__(BLOCK) void yolo_partial(
    const float* __restrict__ pred,
    const float* __restrict__ targ,
    float* __restrict__ partial)
{
    __shared__ float lds[2 * CELLS_PER_BLOCK * STRIDE]; // 31744 B -> 5 blocks/CU
    __shared__ float wsum[BLOCK / 64];

    const int tid = threadIdx.x;
    const size_t gbase = (size_t)blockIdx.x * CELLS_PER_BLOCK * 30;
    const float2* pp = reinterpret_cast<const float2*>(pred + gbase);
    const float2* tp = reinterpret_cast<const float2*>(targ + gbase);

    // ---- coalesced staging: issue all 15 loads first (MLP), then LDS writes
    float2 v[15];
    #pragma unroll
    for (int k = 0; k < 15; ++k) {
        int i = tid + k * BLOCK;                       // 0..3839, exact cover
        const float2* src = (i < F2_PER_INPUT) ? (pp + i) : (tp + (i - F2_PER_INPUT));
        v[k] = *src;
    }
    #pragma unroll
    for (int k = 0; k < 15; ++k) {
        int i = tid + k * BLOCK;
        int ii = (i < F2_PER_INPUT) ? i : (i - F2_PER_INPUT);
        int cell = ii / 15;
        int elem = 2 * (ii % 15);                      // even, never straddles a cell
        int off = ((i < F2_PER_INPUT) ? 0 : CELLS_PER_BLOCK * STRIDE)
                  + cell * STRIDE + elem;
        lds[off]     = v[k].x;
        lds[off + 1] = v[k].y;
    }
    __syncthreads();

    // ---- compute: waves 0-1 do box math for cell=tid; waves 2-3 do class loss
    float loss = 0.0f;
    if (tid < CELLS_PER_BLOCK) {
        const float* pc = &lds[tid * STRIDE];
        const float* tc = &lds[CELLS_PER_BLOCK * STRIDE + tid * STRIDE];

        float pv0 = pc[0], pv1 = pc[1], pv2 = pc[2], pv3 = pc[3], pv4 = pc[4];
        float pv5 = pc[5], pv6 = pc[6], pv7 = pc[7], pv8 = pc[8], pv9 = pc[9];
        float tv0 = tc[0], tv1 = tc[1], tv2 = tc[2], tv3 = tc[3], tv4 = tc[4];
        float tv5 = tc[5], tv6 = tc[6], tv7 = tc[7], tv8 = tc[8];

        bool obj = tv4 > 0.0f;

        if (!obj) {
            float d4 = pv4 - tv4;
            float d9 = pv9 - tc[9];
            loss = 0.5f * (d4 * d4 + d9 * d9);
        } else {
            // target box 0 corners
            float tcx = tv0 / 14.0f, tcy = tv1 / 14.0f;
            float t_ltx = tcx - 0.5f * tv2;
            float t_lty = tcy - 0.5f * tv3;
            float t_rbx = tcx + 0.5f * tv2;
            float t_rby = tcy + 0.5f * tv3;
            float area_t = (t_rbx - t_ltx) * (t_rby - t_lty);

            // pred box 0
            float p0cx = pv0 / 14.0f, p0cy = pv1 / 14.0f;
            float p0_ltx = p0cx - 0.5f * pv2;
            float p0_lty = p0cy - 0.5f * pv3;
            float p0_rbx = p0cx + 0.5f * pv2;
            float p0_rby = p0cy + 0.5f * pv3;
            float w0x = fmaxf(fminf(p0_rbx, t_rbx) - fmaxf(p0_ltx, t_ltx), 0.0f);
            float w0y = fmaxf(fminf(p0_rby, t_rby) - fmaxf(p0_lty, t_lty), 0.0f);
            float inter0 = w0x * w0y;
            float area_p0 = (p0_rbx - p0_ltx) * (p0_rby - p0_lty);
            float iou0 = inter0 / (area_p0 + area_t - inter0);

            // pred box 1
            float p1cx = pv5 / 14.0f, p1cy = pv6 / 14.0f;
            float p1_ltx = p1cx - 0.5f * pv7;
            float p1_lty = p1cy - 0.5f * pv8;
            float p1_rbx = p1cx + 0.5f * pv7;
            float p1_rby = p1cy + 0.5f * pv8;
            float w1x = fmaxf(fminf(p1_rbx, t_rbx) - fmaxf(p1_ltx, t_ltx), 0.0f);
            float w1y = fmaxf(fminf(p1_rby, t_rby) - fmaxf(p1_lty, t_lty), 0.0f);
            float inter1 = w1x * w1y;
            float area_p1 = (p1_rbx - p1_ltx) * (p1_rby - p1_lty);
            float iou1 = inter1 / (area_p1 + area_t - inter1);

            bool best1 = iou1 > iou0;          // tie -> box 0 (argmax first-occurrence)
            float max_iou = fmaxf(iou0, iou1);

            float pbr0 = best1 ? pv5 : pv0;
            float pbr1 = best1 ? pv6 : pv1;
            float pbr2 = best1 ? pv7 : pv2;
            float pbr3 = best1 ? pv8 : pv3;
            float pbr4 = best1 ? pv9 : pv4;
            float tbr0 = best1 ? tv5 : tv0;
            float tbr1 = best1 ? tv6 : tv1;
            float tbr2 = best1 ? tv7 : tv2;
            float tbr3 = best1 ? tv8 : tv3;

            float dcf = pbr4 - max_iou;
            float contain = dcf * dcf;

            float dx = pbr0 - tbr0;
            float dy = pbr1 - tbr1;
            float reg_xy = dx * dx + dy * dy;

            float dw = sqrtf(pbr2) - sqrtf(tbr2);
            float dh = sqrtf(pbr3) - sqrtf(tbr3);
            float reg_wh = dw * dw + dh * dh;

            loss = contain + 5.0f * (reg_xy + reg_wh);
        }
    } else {
        // class loss for cell = tid - 128 (only when obj)
        int c = tid - CELLS_PER_BLOCK;
        const float* pc = &lds[c * STRIDE];
        const float* tc = &lds[CELLS_PER_BLOCK * STRIDE + c * STRIDE];
        if (tc[4] > 0.0f) {
            float cls = 0.0f;
            #pragma unroll
            for (int e = 10; e < 30; ++e) {
                float d = pc[e] - tc[e];
                cls += d * d;
            }
            loss = cls;
        }
    }

    // ---- block reduction
    #pragma unroll
    for (int off = 32; off > 0; off >>= 1)
        loss += __shfl_down(loss, off, 64);

    int lane = tid & 63;
    int wid = tid >> 6;
    if (lane == 0) wsum[wid] = loss;
    __syncthreads();
    if (tid == 0)
        partial[blockIdx.x] = wsum[0] + wsum[1] + wsum[2] + wsum[3];
}

__global__ __launch_bounds__(1024) void yolo_final(
    const float* __restrict__ partial,
    float* __restrict__ out)
{
    float s = 0.0f;
    for (int i = threadIdx.x; i < NBLOCKS; i += 1024)
        s += partial[i];

    #pragma unroll
    for (int off = 32; off > 0; off >>= 1)
        s += __shfl_down(s, off, 64);

    __shared__ float wsum[16];
    int lane = threadIdx.x & 63;
    int wid = threadIdx.x >> 6;
    if (lane == 0) wsum[wid] = s;
    __syncthreads();
    if (threadIdx.x == 0) {
        float tot = 0.0f;
        #pragma unroll
        for (int w = 0; w < 16; ++w) tot += wsum[w];
        out[0] = tot * (1.0f / 4096.0f);
    }
}

extern "C" void kernel_launch(void* const* d_in, const int* in_sizes, int n_in,
                              void* d_out, int out_size, void* d_ws, size_t ws_size,
                              hipStream_t stream) {
    const float* pred = (const float*)d_in[0];
    const float* targ = (const float*)d_in[1];
    float* out = (float*)d_out;
    float* partial = (float*)d_ws;

    yolo_partial<<<NBLOCKS, BLOCK, 0, stream>>>(pred, targ, partial);
    yolo_final<<<1, 1024, 0, stream>>>(partial, out);
}